// Round 3
// baseline (168.780 us; speedup 1.0000x reference)
//
#include <hip/hip_runtime.h>
#include <math.h>

#define NG 16
#define GW 128
#define NEGV -1.0e9f
#define EPSBN 1e-5f
#define MIN_SCORE 0.1f
#define TOLK 1e-7f
#define NBIN 1024
#define NPBMAX 256
#define EPT 4            // edges per thread in scatter

// ---------- helpers ----------
__device__ __forceinline__ unsigned encf(float f) {
  unsigned u = __float_as_uint(f);
  return (u & 0x80000000u) ? ~u : (u | 0x80000000u);
}
__device__ __forceinline__ float decf(unsigned u) {
  unsigned b = (u & 0x80000000u) ? (u & 0x7fffffffu) : ~u;
  return __uint_as_float(b);
}
__device__ __forceinline__ float eluf(float v) { return v > 0.0f ? v : expm1f(v); }

// ---------- kernels ----------
__global__ void k_zero(int* __restrict__ hist) {
  hist[threadIdx.x] = 0;   // 1 block x NBIN threads
}

// histogram + all idempotent init stores
__global__ __launch_bounds__(1024) void k_hist(
    const int* __restrict__ dst, int ne, int shift, int* __restrict__ hist,
    const float* __restrict__ x, const float* __restrict__ gcn_w,
    float* __restrict__ xw, unsigned* __restrict__ smax_e,
    float* __restrict__ sumex, unsigned* __restrict__ gmax_e, int n) {
  __shared__ int lh[NBIN];
  int t = threadIdx.x;
  for (int b = t; b < NBIN; b += blockDim.x) lh[b] = 0;
  __syncthreads();
  int gid = blockIdx.x * blockDim.x + t;
  int gs = gridDim.x * blockDim.x;
  if (gid < NG) { smax_e[gid] = encf(-INFINITY); sumex[gid] = 0.0f; }
  if (gid < NG * 3 * GW) gmax_e[gid] = encf(NEGV);
  float w0 = gcn_w[0], w1 = gcn_w[1];
  for (int i = gid; i < n; i += gs) xw[i] = x[2 * i] * w0 + x[2 * i + 1] * w1;
  for (int e = gid; e < ne; e += gs) atomicAdd(&lh[dst[e] >> shift], 1);
  __syncthreads();
  for (int b = t; b < NBIN; b += blockDim.x)
    if (lh[b]) atomicAdd(&hist[b], lh[b]);
}

__global__ void k_prefix(const int* __restrict__ hist, int* __restrict__ base,
                         int* __restrict__ cursor, int* __restrict__ counters) {
  __shared__ int s[NBIN];
  int t = threadIdx.x;
  if (t == 0) { counters[0] = 0; counters[1] = 0; }
  s[t] = hist[t];
  __syncthreads();
  for (int o = 1; o < NBIN; o <<= 1) {
    int v = (t >= o) ? s[t - o] : 0;
    __syncthreads();
    s[t] += v;
    __syncthreads();
  }
  int ex = s[t] - hist[t];
  base[t] = ex;
  cursor[t] = ex;
}

// sort edges by dst-bucket; payload = (dst_local<<24) | src  (n < 2^24, NPB<=256)
__global__ __launch_bounds__(1024) void k_scatter(
    const int* __restrict__ src, const int* __restrict__ dst, int ne, int shift,
    int* __restrict__ cursor, unsigned* __restrict__ sorted) {
  __shared__ int lh[NBIN];
  __shared__ int gb[NBIN];
  int t = threadIdx.x;
  for (int b = t; b < NBIN; b += blockDim.x) lh[b] = 0;
  __syncthreads();
  int ebase = blockIdx.x * (1024 * EPT);
  int rank[EPT], dv[EPT];
  #pragma unroll
  for (int k = 0; k < EPT; ++k) {
    int e = ebase + k * 1024 + t;
    rank[k] = 0; dv[k] = 0;
    if (e < ne) {
      dv[k] = dst[e];
      rank[k] = atomicAdd(&lh[dv[k] >> shift], 1);
    }
  }
  __syncthreads();
  for (int b = t; b < NBIN; b += blockDim.x) {
    gb[b] = 0;
    if (lh[b]) gb[b] = atomicAdd(&cursor[b], lh[b]);
  }
  __syncthreads();
  #pragma unroll
  for (int k = 0; k < EPT; ++k) {
    int e = ebase + k * 1024 + t;
    if (e < ne) {
      int d = dv[k];
      int bin = d >> shift;
      int dl = d - (bin << shift);
      sorted[gb[bin] + rank[k]] = ((unsigned)dl << 24) | (unsigned)src[e];
    }
  }
}

// per-bucket: deg count (LDS) -> dinv + y = xw*dinv
__global__ void k_c1(const unsigned* __restrict__ sorted, const int* __restrict__ base,
                     const int* __restrict__ hist, const float* __restrict__ xw,
                     float* __restrict__ dinv, float* __restrict__ y,
                     int n, int shift) {
  __shared__ int ldeg[NPBMAX];
  int b = blockIdx.x;
  int off = b << shift;
  if (off >= n) return;
  int npb = 1 << shift;
  int t = threadIdx.x;
  for (int j = t; j < npb; j += blockDim.x) ldeg[j] = 0;
  __syncthreads();
  int s0 = base[b], cnt = hist[b];
  for (int i = t; i < cnt; i += blockDim.x)
    atomicAdd(&ldeg[sorted[s0 + i] >> 24], 1);
  __syncthreads();
  for (int j = t; j < npb; j += blockDim.x) {
    int g = off + j;
    if (g < n) {
      float dv = rsqrtf((float)(ldeg[j] + 1));   // +1 self loop
      dinv[g] = dv;
      y[g] = xw[g] * dv;
    }
  }
}

// per-bucket: t[d] = sum y[src]; then attn -> s_raw + per-graph max
__global__ void k_c2(const unsigned* __restrict__ sorted, const int* __restrict__ base,
                     const int* __restrict__ hist, const float* __restrict__ y,
                     const float* __restrict__ xw, const float* __restrict__ dinv,
                     const int* __restrict__ batch, const float* __restrict__ gcn_b,
                     const float* __restrict__ topk_w, float* __restrict__ s_raw,
                     unsigned* __restrict__ smax_e, int n, int shift) {
  __shared__ float lt[NPBMAX];
  __shared__ unsigned ls[NG];
  int b = blockIdx.x;
  int off = b << shift;
  if (off >= n) return;
  int npb = 1 << shift;
  int t = threadIdx.x;
  for (int j = t; j < npb; j += blockDim.x) lt[j] = 0.0f;
  if (t < NG) ls[t] = encf(-INFINITY);
  __syncthreads();
  int s0 = base[b], cnt = hist[b];
  for (int i = t; i < cnt; i += blockDim.x) {
    unsigned p = sorted[s0 + i];
    atomicAdd(&lt[p >> 24], y[p & 0xFFFFFFu]);
  }
  __syncthreads();
  float gb_ = gcn_b[0], tw = topk_w[0];
  for (int j = t; j < npb; j += blockDim.x) {
    int g = off + j;
    if (g < n) {
      float dv = dinv[g];
      float attn = dv * lt[j] + xw[g] * dv * dv + gb_;
      float s = attn * tw;
      s_raw[g] = s;
      atomicMax(&ls[batch[g]], encf(s));
    }
  }
  __syncthreads();
  if (t < NG && ls[t] != encf(-INFINITY)) atomicMax(&smax_e[t], ls[t]);
}

__global__ void k_ex(const float* __restrict__ s_raw, const int* __restrict__ batch,
                     const unsigned* __restrict__ smax_e, float* __restrict__ ex,
                     float* __restrict__ sumex, int n) {
  __shared__ float lsum[NG];
  int t = threadIdx.x;
  if (t < NG) lsum[t] = 0.0f;
  __syncthreads();
  int i = blockIdx.x * blockDim.x + t;
  if (i < n) {
    int b = batch[i];
    float e = expf(s_raw[i] - decf(smax_e[b]));
    ex[i] = e;
    atomicAdd(&lsum[b], e);
  }
  __syncthreads();
  if (t < NG && lsum[t] != 0.0f) atomicAdd(&sumex[t], lsum[t]);
}

__global__ void k_compact_n(const float* __restrict__ ex, const float* __restrict__ sumex,
                            const int* __restrict__ batch, const float* __restrict__ x,
                            int* __restrict__ kmap, int* __restrict__ kbatch,
                            float* __restrict__ hk, float* __restrict__ tx0,
                            float* __restrict__ degfc, int* __restrict__ counters,
                            int n, int kcap) {
  int i = blockIdx.x * blockDim.x + threadIdx.x;
  if (i >= n) return;
  if (i < kcap) degfc[i] = 0.0f;                   // idempotent pre-zero for compact_e
  int b = batch[i];
  float se = sumex[b];
  float score = ex[i] / se;
  float thr = fminf(1.0f / se - TOLK, MIN_SCORE);  // max(score) == fl(1/se) exactly
  int m = -1;
  if (score > thr) {
    int idx = atomicAdd(&counters[0], 1);
    if (idx < kcap) {
      m = idx;
      kbatch[idx] = b;
      hk[2 * idx] = x[2 * i] * score;
      hk[2 * idx + 1] = x[2 * i + 1] * score;
      tx0[2 * idx] = 0.0f;
      tx0[2 * idx + 1] = 0.0f;
    }
  }
  kmap[i] = m;
}

// bucket-based surviving-edge compaction (reads sorted once, 4B/edge)
__global__ void k_compact_e(const unsigned* __restrict__ sorted, const int* __restrict__ base,
                            const int* __restrict__ hist, const int* __restrict__ kmap,
                            int* __restrict__ eks, int* __restrict__ ekd,
                            float* __restrict__ degfc, int* __restrict__ counters,
                            int n, int shift, int ecap) {
  int b = blockIdx.x;
  int off = b << shift;
  if (off >= n) return;
  int s0 = base[b], cnt = hist[b];
  for (int i = threadIdx.x; i < cnt; i += blockDim.x) {
    unsigned p = sorted[s0 + i];
    int ks = kmap[p & 0xFFFFFFu];
    if (ks < 0) continue;
    int kd = kmap[off + (int)(p >> 24)];
    if (kd < 0) continue;
    int j = atomicAdd(&counters[1], 1);
    if (j < ecap) {
      eks[j] = ks;
      ekd[j] = kd;
      atomicAdd(&degfc[kd], 1.0f);
    }
  }
}

// one block does the entire post-pool network: 3x(edge_agg + cheb/bn) + MLP + log_softmax
__global__ __launch_bounds__(1024) void k_tail(
    const float* __restrict__ hk, float* __restrict__ tx0,
    const float* __restrict__ c0w0, const float* __restrict__ c0w1, const float* __restrict__ c0b,
    const float* __restrict__ c1w0, const float* __restrict__ c1w1, const float* __restrict__ c1b,
    const float* __restrict__ c2w0, const float* __restrict__ c2w1, const float* __restrict__ c2b,
    const float* __restrict__ bng, const float* __restrict__ bnb,
    const float* __restrict__ bnm, const float* __restrict__ bnv,
    const int* __restrict__ kbatch, const int* __restrict__ counters, int kcap, int ecap,
    const int* __restrict__ eks, const int* __restrict__ ekd, const float* __restrict__ degfc,
    float* __restrict__ hA, float* __restrict__ hB, float* __restrict__ tx,
    unsigned* __restrict__ gmax_e,
    const float* __restrict__ l0w, const float* __restrict__ l0b,
    const float* __restrict__ l1w, const float* __restrict__ l1b,
    const float* __restrict__ lfw, const float* __restrict__ lfb,
    float* __restrict__ out) {
  __shared__ float gv[NG * 3 * GW];   // 24 KB
  __shared__ float t0s[NG * 32];
  __shared__ float t1s[NG * 8];
  __shared__ float lgs[NG * 3];
  int t = threadIdx.x;
  int K = counters[0]; if (K > kcap) K = kcap;
  int S = counters[1]; if (S > ecap) S = ecap;

  // --- edge agg layer 0 (D=2) into tx0 ---
  for (int idx = t; idx < S * 2; idx += 1024) {
    int e = idx >> 1, c = idx & 1;
    int ks = eks[e], kd = ekd[e];
    float dfs = degfc[ks], dfd = degfc[kd];
    float nf = (dfs > 0.0f ? rsqrtf(dfs) : 0.0f) * (dfd > 0.0f ? rsqrtf(dfd) : 0.0f);
    atomicAdd(&tx0[kd * 2 + c], -hk[ks * 2 + c] * nf);
  }
  __syncthreads();
  // --- mm0 (DIN=2) -> hA ; zero tx for layer 1 ---
  for (int o = t; o < K * GW; o += 1024) {
    int i = o >> 7, j = o & 127;
    float acc = c0b[j] + hk[2 * i] * c0w0[j] + hk[2 * i + 1] * c0w0[GW + j]
              + tx0[2 * i] * c0w1[j] + tx0[2 * i + 1] * c0w1[GW + j];
    float v = eluf(acc);
    v = (v - bnm[j]) * (bng[j] * rsqrtf(bnv[j] + EPSBN)) + bnb[j];
    hA[o] = v;
    atomicMax(&gmax_e[kbatch[i] * (3 * GW) + j], encf(v));
    tx[o] = 0.0f;
  }
  __syncthreads();
  // --- edge agg layer 1 (D=128) into tx ---
  for (int idx = t; idx < S * GW; idx += 1024) {
    int e = idx >> 7, c = idx & 127;
    int ks = eks[e], kd = ekd[e];
    float dfs = degfc[ks], dfd = degfc[kd];
    float nf = (dfs > 0.0f ? rsqrtf(dfs) : 0.0f) * (dfd > 0.0f ? rsqrtf(dfd) : 0.0f);
    atomicAdd(&tx[kd * GW + c], -hA[ks * GW + c] * nf);
  }
  __syncthreads();
  // --- mm1 -> hB ---
  for (int o = t; o < K * GW; o += 1024) {
    int i = o >> 7, j = o & 127;
    float acc = c1b[j];
    for (int k = 0; k < GW; ++k)
      acc += hA[i * GW + k] * c1w0[k * GW + j] + tx[i * GW + k] * c1w1[k * GW + j];
    float v = eluf(acc);
    v = (v - bnm[GW + j]) * (bng[GW + j] * rsqrtf(bnv[GW + j] + EPSBN)) + bnb[GW + j];
    hB[o] = v;
    atomicMax(&gmax_e[kbatch[i] * (3 * GW) + GW + j], encf(v));
  }
  __syncthreads();
  // --- re-zero tx for layer 2 (separate phase: mm1 read tx) ---
  for (int o = t; o < K * GW; o += 1024) tx[o] = 0.0f;
  __syncthreads();
  // --- edge agg layer 2 into tx ---
  for (int idx = t; idx < S * GW; idx += 1024) {
    int e = idx >> 7, c = idx & 127;
    int ks = eks[e], kd = ekd[e];
    float dfs = degfc[ks], dfd = degfc[kd];
    float nf = (dfs > 0.0f ? rsqrtf(dfs) : 0.0f) * (dfd > 0.0f ? rsqrtf(dfd) : 0.0f);
    atomicAdd(&tx[kd * GW + c], -hB[ks * GW + c] * nf);
  }
  __syncthreads();
  // --- mm2 (no h store, gmax only) ---
  for (int o = t; o < K * GW; o += 1024) {
    int i = o >> 7, j = o & 127;
    float acc = c2b[j];
    for (int k = 0; k < GW; ++k)
      acc += hB[i * GW + k] * c2w0[k * GW + j] + tx[i * GW + k] * c2w1[k * GW + j];
    float v = eluf(acc);
    v = (v - bnm[2 * GW + j]) * (bng[2 * GW + j] * rsqrtf(bnv[2 * GW + j] + EPSBN)) + bnb[2 * GW + j];
    atomicMax(&gmax_e[kbatch[i] * (3 * GW) + 2 * GW + j], encf(v));
  }
  __syncthreads();
  // --- stage gmax into LDS via atomic reads (L2-coherent) ---
  for (int o = t; o < NG * 3 * GW; o += 1024)
    gv[o] = decf(atomicMax(&gmax_e[o], 0u));
  __syncthreads();
  // --- MLP: lin0 (384->32) ---
  if (t < NG * 32) {
    int g = t >> 5, j = t & 31;
    float acc = l0b[j];
    for (int k = 0; k < 3 * GW; ++k) acc += gv[g * 3 * GW + k] * l0w[k * 32 + j];
    t0s[t] = eluf(acc);
  }
  __syncthreads();
  if (t < NG * 8) {
    int g = t >> 3, j = t & 7;
    float acc = l1b[j];
    for (int k = 0; k < 32; ++k) acc += t0s[g * 32 + k] * l1w[k * 8 + j];
    t1s[t] = eluf(acc);
  }
  __syncthreads();
  if (t < NG * 3) {
    int g = t / 3, j = t - 3 * g;
    float acc = lfb[j];
    for (int k = 0; k < 8; ++k) acc += t1s[g * 8 + k] * lfw[k * 3 + j];
    lgs[t] = acc;
  }
  __syncthreads();
  if (t < NG) {
    float a = lgs[t * 3], b = lgs[t * 3 + 1], c = lgs[t * 3 + 2];
    float m = fmaxf(a, fmaxf(b, c));
    float ls = m + logf(expf(a - m) + expf(b - m) + expf(c - m));
    out[t * 3 + 0] = a - ls;
    out[t * 3 + 1] = b - ls;
    out[t * 3 + 2] = c - ls;
  }
}

// ---------- launcher ----------
extern "C" void kernel_launch(void* const* d_in, const int* in_sizes, int n_in,
                              void* d_out, int out_size, void* d_ws, size_t ws_size,
                              hipStream_t stream) {
  const float* x      = (const float*)d_in[0];
  const int*   ei     = (const int*)d_in[1];
  const int*   batch  = (const int*)d_in[2];
  const float* gcn_w  = (const float*)d_in[3];
  const float* gcn_b  = (const float*)d_in[4];
  const float* topk_w = (const float*)d_in[5];
  const float* c0w0 = (const float*)d_in[6],  *c0w1 = (const float*)d_in[7],  *c0b = (const float*)d_in[8];
  const float* c1w0 = (const float*)d_in[9],  *c1w1 = (const float*)d_in[10], *c1b = (const float*)d_in[11];
  const float* c2w0 = (const float*)d_in[12], *c2w1 = (const float*)d_in[13], *c2b = (const float*)d_in[14];
  const float* bng = (const float*)d_in[15], *bnb = (const float*)d_in[16];
  const float* bnm = (const float*)d_in[17], *bnv = (const float*)d_in[18];
  const float* l0w = (const float*)d_in[19], *l0b = (const float*)d_in[20];
  const float* l1w = (const float*)d_in[21], *l1b = (const float*)d_in[22];
  const float* lfw = (const float*)d_in[23], *lfb = (const float*)d_in[24];
  float* out = (float*)d_out;

  const int n  = in_sizes[2];       // N nodes
  const int ne = in_sizes[1] / 2;   // E edges
  const int* src = ei;
  const int* dst = ei + ne;

  // bucket shift: smallest with (n-1)>>shift < NBIN; NPB = 1<<shift (<= NPBMAX)
  int shift = 0;
  while (((n - 1) >> shift) >= NBIN) shift++;
  if (shift > 8) shift = 8;  // supports n <= 262144

  int kcap = 4096, ecap = 65536;
  auto tneed = [&](size_t kc, size_t ec) -> size_t {
    auto al = [](size_t b) { return (b + 255) & ~(size_t)255; };
    size_t t = 0;
    t += al((size_t)n * 4) * 6;               // xw, dinv, y, s_raw, ex, kmap
    t += al((size_t)ne * 4);                  // sorted
    t += al(NBIN * 4) * 3;                    // hist, base, cursor
    t += al(NG * 4) * 2;                      // smax_e, sumex
    t += al(NG * 3 * GW * 4);                 // gmax_e
    t += al(8);                               // counters
    t += al(kc * 4) * 2;                      // kbatch, degfc
    t += al(kc * 8) * 2;                      // hk, tx0
    t += al(kc * GW * 4) * 3;                 // hA, hB, tx
    t += al(ec * 4) * 2;                      // eks, ekd
    return t;
  };
  while (kcap > 128 && tneed(kcap, ecap) > ws_size) { kcap >>= 1; ecap >>= 1; }

  char* bp = (char*)d_ws;
  size_t off = 0;
  auto A = [&](size_t bytes) -> void* {
    void* r = (void*)(bp + off);
    off += (bytes + 255) & ~(size_t)255;
    return r;
  };
  float*    xw     = (float*)A((size_t)n * 4);
  float*    dinv   = (float*)A((size_t)n * 4);
  float*    y      = (float*)A((size_t)n * 4);
  float*    s_raw  = (float*)A((size_t)n * 4);
  float*    ex     = (float*)A((size_t)n * 4);
  int*      kmap   = (int*)A((size_t)n * 4);
  unsigned* sorted = (unsigned*)A((size_t)ne * 4);
  int*      hist   = (int*)A(NBIN * 4);
  int*      binb   = (int*)A(NBIN * 4);
  int*      cursor = (int*)A(NBIN * 4);
  unsigned* smax_e = (unsigned*)A(NG * 4);
  float*    sumex  = (float*)A(NG * 4);
  unsigned* gmax_e = (unsigned*)A(NG * 3 * GW * 4);
  int*      counters = (int*)A(8);
  int*      kbatch = (int*)A((size_t)kcap * 4);
  float*    degfc  = (float*)A((size_t)kcap * 4);
  float*    hk     = (float*)A((size_t)kcap * 8);
  float*    tx0    = (float*)A((size_t)kcap * 8);
  float*    hA     = (float*)A((size_t)kcap * GW * 4);
  float*    hB     = (float*)A((size_t)kcap * GW * 4);
  float*    tx     = (float*)A((size_t)kcap * GW * 4);
  int*      eks    = (int*)A((size_t)ecap * 4);
  int*      ekd    = (int*)A((size_t)ecap * 4);

  const int nbN = (n + 255) / 256;
  const int nbS = (ne + 1024 * EPT - 1) / (1024 * EPT);

  k_zero<<<1, NBIN, 0, stream>>>(hist);
  k_hist<<<512, 1024, 0, stream>>>(dst, ne, shift, hist, x, gcn_w, xw,
                                   smax_e, sumex, gmax_e, n);
  k_prefix<<<1, NBIN, 0, stream>>>(hist, binb, cursor, counters);
  k_scatter<<<nbS, 1024, 0, stream>>>(src, dst, ne, shift, cursor, sorted);
  k_c1<<<NBIN, 256, 0, stream>>>(sorted, binb, hist, xw, dinv, y, n, shift);
  k_c2<<<NBIN, 256, 0, stream>>>(sorted, binb, hist, y, xw, dinv, batch, gcn_b,
                                 topk_w, s_raw, smax_e, n, shift);
  k_ex<<<nbN, 256, 0, stream>>>(s_raw, batch, smax_e, ex, sumex, n);
  k_compact_n<<<nbN, 256, 0, stream>>>(ex, sumex, batch, x, kmap, kbatch, hk, tx0,
                                       degfc, counters, n, kcap);
  k_compact_e<<<NBIN, 256, 0, stream>>>(sorted, binb, hist, kmap, eks, ekd, degfc,
                                        counters, n, shift, ecap);
  k_tail<<<1, 1024, 0, stream>>>(hk, tx0, c0w0, c0w1, c0b, c1w0, c1w1, c1b,
                                 c2w0, c2w1, c2b, bng, bnb, bnm, bnv,
                                 kbatch, counters, kcap, ecap, eks, ekd, degfc,
                                 hA, hB, tx, gmax_e, l0w, l0b, l1w, l1b, lfw, lfb, out);
}

// Round 4
// 124.859 us; speedup vs baseline: 1.3518x; 1.3518x over previous
//
#include <hip/hip_runtime.h>
#include <math.h>

#define NG 16
#define GW 128
#define NEGV -1.0e9f
#define EPSBN 1e-5f
#define MIN_SCORE 0.1f
#define TOLK 1e-7f
#define NBIN 1024
#define NPBMAX 256
#define EPT 4            // edges per thread in scatter

// ---------- helpers ----------
__device__ __forceinline__ unsigned encf(float f) {
  unsigned u = __float_as_uint(f);
  return (u & 0x80000000u) ? ~u : (u | 0x80000000u);
}
__device__ __forceinline__ float decf(unsigned u) {
  unsigned b = (u & 0x80000000u) ? (u & 0x7fffffffu) : ~u;
  return __uint_as_float(b);
}
__device__ __forceinline__ float eluf(float v) { return v > 0.0f ? v : expm1f(v); }

// ---------- kernels ----------
__global__ void k_zero(int* __restrict__ hist) {
  hist[threadIdx.x] = 0;   // 1 block x NBIN threads
}

// histogram + all idempotent init stores
__global__ __launch_bounds__(1024) void k_hist(
    const int* __restrict__ dst, int ne, int shift, int* __restrict__ hist,
    const float* __restrict__ x, const float* __restrict__ gcn_w,
    float* __restrict__ xw, unsigned* __restrict__ smax_e,
    float* __restrict__ sumex, unsigned* __restrict__ gmax_e, int n) {
  __shared__ int lh[NBIN];
  int t = threadIdx.x;
  for (int b = t; b < NBIN; b += blockDim.x) lh[b] = 0;
  __syncthreads();
  int gid = blockIdx.x * blockDim.x + t;
  int gs = gridDim.x * blockDim.x;
  if (gid < NG) { smax_e[gid] = encf(-INFINITY); sumex[gid] = 0.0f; }
  if (gid < NG * 3 * GW) gmax_e[gid] = encf(NEGV);
  float w0 = gcn_w[0], w1 = gcn_w[1];
  for (int i = gid; i < n; i += gs) xw[i] = x[2 * i] * w0 + x[2 * i + 1] * w1;
  for (int e = gid; e < ne; e += gs) atomicAdd(&lh[dst[e] >> shift], 1);
  __syncthreads();
  for (int b = t; b < NBIN; b += blockDim.x)
    if (lh[b]) atomicAdd(&hist[b], lh[b]);
}

__global__ void k_prefix(const int* __restrict__ hist, int* __restrict__ base,
                         int* __restrict__ cursor, int* __restrict__ counters) {
  __shared__ int s[NBIN];
  int t = threadIdx.x;
  if (t == 0) { counters[0] = 0; counters[1] = 0; }
  s[t] = hist[t];
  __syncthreads();
  for (int o = 1; o < NBIN; o <<= 1) {
    int v = (t >= o) ? s[t - o] : 0;
    __syncthreads();
    s[t] += v;
    __syncthreads();
  }
  int ex = s[t] - hist[t];
  base[t] = ex;
  cursor[t] = ex;
}

// sort edges by dst-bucket; payload = (dst_local<<24) | src  (n < 2^24, NPB<=256)
__global__ __launch_bounds__(1024) void k_scatter(
    const int* __restrict__ src, const int* __restrict__ dst, int ne, int shift,
    int* __restrict__ cursor, unsigned* __restrict__ sorted) {
  __shared__ int lh[NBIN];
  __shared__ int gb[NBIN];
  int t = threadIdx.x;
  for (int b = t; b < NBIN; b += blockDim.x) lh[b] = 0;
  __syncthreads();
  int ebase = blockIdx.x * (1024 * EPT);
  int rank[EPT], dv[EPT];
  #pragma unroll
  for (int k = 0; k < EPT; ++k) {
    int e = ebase + k * 1024 + t;
    rank[k] = 0; dv[k] = 0;
    if (e < ne) {
      dv[k] = dst[e];
      rank[k] = atomicAdd(&lh[dv[k] >> shift], 1);
    }
  }
  __syncthreads();
  for (int b = t; b < NBIN; b += blockDim.x) {
    gb[b] = 0;
    if (lh[b]) gb[b] = atomicAdd(&cursor[b], lh[b]);
  }
  __syncthreads();
  #pragma unroll
  for (int k = 0; k < EPT; ++k) {
    int e = ebase + k * 1024 + t;
    if (e < ne) {
      int d = dv[k];
      int bin = d >> shift;
      int dl = d - (bin << shift);
      sorted[gb[bin] + rank[k]] = ((unsigned)dl << 24) | (unsigned)src[e];
    }
  }
}

// per-bucket: deg count (LDS) -> dinv + y = xw*dinv
__global__ void k_c1(const unsigned* __restrict__ sorted, const int* __restrict__ base,
                     const int* __restrict__ hist, const float* __restrict__ xw,
                     float* __restrict__ dinv, float* __restrict__ y,
                     int n, int shift) {
  __shared__ int ldeg[NPBMAX];
  int b = blockIdx.x;
  int off = b << shift;
  if (off >= n) return;
  int npb = 1 << shift;
  int t = threadIdx.x;
  for (int j = t; j < npb; j += blockDim.x) ldeg[j] = 0;
  __syncthreads();
  int s0 = base[b], cnt = hist[b];
  for (int i = t; i < cnt; i += blockDim.x)
    atomicAdd(&ldeg[sorted[s0 + i] >> 24], 1);
  __syncthreads();
  for (int j = t; j < npb; j += blockDim.x) {
    int g = off + j;
    if (g < n) {
      float dv = rsqrtf((float)(ldeg[j] + 1));   // +1 self loop
      dinv[g] = dv;
      y[g] = xw[g] * dv;
    }
  }
}

// per-bucket: t[d] = sum y[src]; then attn -> s_raw + per-graph max
__global__ void k_c2(const unsigned* __restrict__ sorted, const int* __restrict__ base,
                     const int* __restrict__ hist, const float* __restrict__ y,
                     const float* __restrict__ xw, const float* __restrict__ dinv,
                     const int* __restrict__ batch, const float* __restrict__ gcn_b,
                     const float* __restrict__ topk_w, float* __restrict__ s_raw,
                     unsigned* __restrict__ smax_e, int n, int shift) {
  __shared__ float lt[NPBMAX];
  __shared__ unsigned ls[NG];
  int b = blockIdx.x;
  int off = b << shift;
  if (off >= n) return;
  int npb = 1 << shift;
  int t = threadIdx.x;
  for (int j = t; j < npb; j += blockDim.x) lt[j] = 0.0f;
  if (t < NG) ls[t] = encf(-INFINITY);
  __syncthreads();
  int s0 = base[b], cnt = hist[b];
  for (int i = t; i < cnt; i += blockDim.x) {
    unsigned p = sorted[s0 + i];
    atomicAdd(&lt[p >> 24], y[p & 0xFFFFFFu]);
  }
  __syncthreads();
  float gb_ = gcn_b[0], tw = topk_w[0];
  for (int j = t; j < npb; j += blockDim.x) {
    int g = off + j;
    if (g < n) {
      float dv = dinv[g];
      float attn = dv * lt[j] + xw[g] * dv * dv + gb_;
      float s = attn * tw;
      s_raw[g] = s;
      atomicMax(&ls[batch[g]], encf(s));
    }
  }
  __syncthreads();
  if (t < NG && ls[t] != encf(-INFINITY)) atomicMax(&smax_e[t], ls[t]);
}

__global__ void k_ex(const float* __restrict__ s_raw, const int* __restrict__ batch,
                     const unsigned* __restrict__ smax_e, float* __restrict__ ex,
                     float* __restrict__ sumex, int n) {
  __shared__ float lsum[NG];
  int t = threadIdx.x;
  if (t < NG) lsum[t] = 0.0f;
  __syncthreads();
  int i = blockIdx.x * blockDim.x + t;
  if (i < n) {
    int b = batch[i];
    float e = expf(s_raw[i] - decf(smax_e[b]));
    ex[i] = e;
    atomicAdd(&lsum[b], e);
  }
  __syncthreads();
  if (t < NG && lsum[t] != 0.0f) atomicAdd(&sumex[t], lsum[t]);
}

__global__ void k_compact_n(const float* __restrict__ ex, const float* __restrict__ sumex,
                            const int* __restrict__ batch, const float* __restrict__ x,
                            int* __restrict__ kmap, int* __restrict__ kbatch,
                            float* __restrict__ hk, float* __restrict__ tx0,
                            float* __restrict__ degfc, int* __restrict__ counters,
                            int n, int kcap) {
  int i = blockIdx.x * blockDim.x + threadIdx.x;
  if (i >= n) return;
  if (i < kcap) degfc[i] = 0.0f;                   // idempotent pre-zero for compact_e
  int b = batch[i];
  float se = sumex[b];
  float score = ex[i] / se;
  float thr = fminf(1.0f / se - TOLK, MIN_SCORE);  // max(score) == fl(1/se) exactly
  int m = -1;
  if (score > thr) {
    int idx = atomicAdd(&counters[0], 1);
    if (idx < kcap) {
      m = idx;
      kbatch[idx] = b;
      hk[2 * idx] = x[2 * i] * score;
      hk[2 * idx + 1] = x[2 * i + 1] * score;
      tx0[2 * idx] = 0.0f;
      tx0[2 * idx + 1] = 0.0f;
    }
  }
  kmap[i] = m;
}

// bucket-based surviving-edge compaction (reads sorted once, 4B/edge)
__global__ void k_compact_e(const unsigned* __restrict__ sorted, const int* __restrict__ base,
                            const int* __restrict__ hist, const int* __restrict__ kmap,
                            int* __restrict__ eks, int* __restrict__ ekd,
                            float* __restrict__ degfc, int* __restrict__ counters,
                            int n, int shift, int ecap) {
  int b = blockIdx.x;
  int off = b << shift;
  if (off >= n) return;
  int s0 = base[b], cnt = hist[b];
  for (int i = threadIdx.x; i < cnt; i += blockDim.x) {
    unsigned p = sorted[s0 + i];
    int ks = kmap[p & 0xFFFFFFu];
    if (ks < 0) continue;
    int kd = kmap[off + (int)(p >> 24)];
    if (kd < 0) continue;
    int j = atomicAdd(&counters[1], 1);
    if (j < ecap) {
      eks[j] = ks;
      ekd[j] = kd;
      atomicAdd(&degfc[kd], 1.0f);
    }
  }
}

template <int LOGD>
__global__ void k_edge_agg(const int* __restrict__ eks, const int* __restrict__ ekd,
                           const float* __restrict__ degfc, const float* __restrict__ h_in,
                           float* __restrict__ tx, const int* __restrict__ counters, int ecap) {
  int S = counters[1];
  if (S > ecap) S = ecap;
  const int D = 1 << LOGD;
  long total = (long)S << LOGD;
  long stride = (long)gridDim.x * blockDim.x;
  for (long idx = (long)blockIdx.x * blockDim.x + threadIdx.x; idx < total; idx += stride) {
    int e = (int)(idx >> LOGD);
    int c = (int)(idx & (D - 1));
    int ks = eks[e], kd = ekd[e];
    float dfs = degfc[ks], dfd = degfc[kd];
    float a = dfs > 0.0f ? 1.0f / sqrtf(dfs) : 0.0f;
    float bb = dfd > 0.0f ? 1.0f / sqrtf(dfd) : 0.0f;
    float nf = a * bb;
    atomicAdd(&tx[kd * D + c], -h_in[ks * D + c] * nf);
  }
}

template <int DIN>
__global__ void k_mm(const float* __restrict__ h_in, const float* __restrict__ tx_in,
                     const float* __restrict__ w0, const float* __restrict__ w1,
                     const float* __restrict__ bias, const float* __restrict__ bn_g,
                     const float* __restrict__ bn_b, const float* __restrict__ bn_m,
                     const float* __restrict__ bn_v, int goff,
                     const int* __restrict__ kbatch, const int* __restrict__ counters,
                     int kcap, float* __restrict__ h_out, unsigned* __restrict__ gmax_e,
                     float* __restrict__ tx_next) {
  __shared__ float lh[DIN];
  __shared__ float lt[DIN];
  int K = counters[0];
  if (K > kcap) K = kcap;
  int j = threadIdx.x;  // 0..GW-1
  float scale = bn_g[j] * (1.0f / sqrtf(bn_v[j] + EPSBN));
  float mean = bn_m[j], beta = bn_b[j], bj = bias[j];
  for (int i = blockIdx.x; i < K; i += gridDim.x) {
    if (j < DIN) { lh[j] = h_in[i * DIN + j]; lt[j] = tx_in[i * DIN + j]; }
    __syncthreads();
    float acc = bj;
    #pragma unroll 8
    for (int k = 0; k < DIN; ++k)
      acc += lh[k] * w0[k * GW + j] + lt[k] * w1[k * GW + j];
    float v = eluf(acc);
    v = (v - mean) * scale + beta;
    h_out[i * GW + j] = v;
    atomicMax(&gmax_e[kbatch[i] * (3 * GW) + goff + j], encf(v));
    if (tx_next) tx_next[i * GW + j] = 0.0f;
    __syncthreads();
  }
}

__global__ void k_final(const unsigned* __restrict__ gmax_e,
                        const float* __restrict__ l0w, const float* __restrict__ l0b,
                        const float* __restrict__ l1w, const float* __restrict__ l1b,
                        const float* __restrict__ lfw, const float* __restrict__ lfb,
                        float* __restrict__ out) {
  __shared__ float gv[3 * GW];
  __shared__ float t0[32];
  __shared__ float t1[8];
  __shared__ float lg[3];
  int g = blockIdx.x;
  int t = threadIdx.x;  // 64 threads
  for (int k = t; k < 3 * GW; k += blockDim.x) gv[k] = decf(gmax_e[g * 3 * GW + k]);
  __syncthreads();
  if (t < 32) {
    float acc = l0b[t];
    for (int k = 0; k < 3 * GW; ++k) acc += gv[k] * l0w[k * 32 + t];
    t0[t] = eluf(acc);
  }
  __syncthreads();
  if (t < 8) {
    float acc = l1b[t];
    for (int k = 0; k < 32; ++k) acc += t0[k] * l1w[k * 8 + t];
    t1[t] = eluf(acc);
  }
  __syncthreads();
  if (t < 3) {
    float acc = lfb[t];
    for (int k = 0; k < 8; ++k) acc += t1[k] * lfw[k * 3 + t];
    lg[t] = acc;
  }
  __syncthreads();
  if (t == 0) {
    float m = fmaxf(lg[0], fmaxf(lg[1], lg[2]));
    float s = expf(lg[0] - m) + expf(lg[1] - m) + expf(lg[2] - m);
    float ls = m + logf(s);
    out[g * 3 + 0] = lg[0] - ls;
    out[g * 3 + 1] = lg[1] - ls;
    out[g * 3 + 2] = lg[2] - ls;
  }
}

// ---------- launcher ----------
extern "C" void kernel_launch(void* const* d_in, const int* in_sizes, int n_in,
                              void* d_out, int out_size, void* d_ws, size_t ws_size,
                              hipStream_t stream) {
  const float* x      = (const float*)d_in[0];
  const int*   ei     = (const int*)d_in[1];
  const int*   batch  = (const int*)d_in[2];
  const float* gcn_w  = (const float*)d_in[3];
  const float* gcn_b  = (const float*)d_in[4];
  const float* topk_w = (const float*)d_in[5];
  const float* c0w0 = (const float*)d_in[6],  *c0w1 = (const float*)d_in[7],  *c0b = (const float*)d_in[8];
  const float* c1w0 = (const float*)d_in[9],  *c1w1 = (const float*)d_in[10], *c1b = (const float*)d_in[11];
  const float* c2w0 = (const float*)d_in[12], *c2w1 = (const float*)d_in[13], *c2b = (const float*)d_in[14];
  const float* bng = (const float*)d_in[15], *bnb = (const float*)d_in[16];
  const float* bnm = (const float*)d_in[17], *bnv = (const float*)d_in[18];
  const float* l0w = (const float*)d_in[19], *l0b = (const float*)d_in[20];
  const float* l1w = (const float*)d_in[21], *l1b = (const float*)d_in[22];
  const float* lfw = (const float*)d_in[23], *lfb = (const float*)d_in[24];
  float* out = (float*)d_out;

  const int n  = in_sizes[2];       // N nodes
  const int ne = in_sizes[1] / 2;   // E edges
  const int* src = ei;
  const int* dst = ei + ne;

  // bucket shift: smallest with (n-1)>>shift < NBIN; NPB = 1<<shift (<= NPBMAX)
  int shift = 0;
  while (((n - 1) >> shift) >= NBIN) shift++;
  if (shift > 8) shift = 8;  // supports n <= 262144

  int kcap = 4096, ecap = 65536;
  auto tneed = [&](size_t kc, size_t ec) -> size_t {
    auto al = [](size_t b) { return (b + 255) & ~(size_t)255; };
    size_t t = 0;
    t += al((size_t)n * 4) * 6;               // xw, dinv, y, s_raw, ex, kmap
    t += al((size_t)ne * 4);                  // sorted
    t += al(NBIN * 4) * 3;                    // hist, base, cursor
    t += al(NG * 4) * 2;                      // smax_e, sumex
    t += al(NG * 3 * GW * 4);                 // gmax_e
    t += al(8);                               // counters
    t += al(kc * 4) * 2;                      // kbatch, degfc
    t += al(kc * 8) * 2;                      // hk, tx0
    t += al(kc * GW * 4) * 3;                 // hA, hB, tx
    t += al(ec * 4) * 2;                      // eks, ekd
    return t;
  };
  while (kcap > 128 && tneed(kcap, ecap) > ws_size) { kcap >>= 1; ecap >>= 1; }

  char* bp = (char*)d_ws;
  size_t off = 0;
  auto A = [&](size_t bytes) -> void* {
    void* r = (void*)(bp + off);
    off += (bytes + 255) & ~(size_t)255;
    return r;
  };
  float*    xw     = (float*)A((size_t)n * 4);
  float*    dinv   = (float*)A((size_t)n * 4);
  float*    y      = (float*)A((size_t)n * 4);
  float*    s_raw  = (float*)A((size_t)n * 4);
  float*    ex     = (float*)A((size_t)n * 4);
  int*      kmap   = (int*)A((size_t)n * 4);
  unsigned* sorted = (unsigned*)A((size_t)ne * 4);
  int*      hist   = (int*)A(NBIN * 4);
  int*      binb   = (int*)A(NBIN * 4);
  int*      cursor = (int*)A(NBIN * 4);
  unsigned* smax_e = (unsigned*)A(NG * 4);
  float*    sumex  = (float*)A(NG * 4);
  unsigned* gmax_e = (unsigned*)A(NG * 3 * GW * 4);
  int*      counters = (int*)A(8);
  int*      kbatch = (int*)A((size_t)kcap * 4);
  float*    degfc  = (float*)A((size_t)kcap * 4);
  float*    hk     = (float*)A((size_t)kcap * 8);
  float*    tx0    = (float*)A((size_t)kcap * 8);
  float*    hA     = (float*)A((size_t)kcap * GW * 4);
  float*    hB     = (float*)A((size_t)kcap * GW * 4);
  float*    tx     = (float*)A((size_t)kcap * GW * 4);
  int*      eks    = (int*)A((size_t)ecap * 4);
  int*      ekd    = (int*)A((size_t)ecap * 4);

  const int nbN = (n + 255) / 256;
  const int nbS = (ne + 1024 * EPT - 1) / (1024 * EPT);

  k_zero<<<1, NBIN, 0, stream>>>(hist);
  k_hist<<<512, 1024, 0, stream>>>(dst, ne, shift, hist, x, gcn_w, xw,
                                   smax_e, sumex, gmax_e, n);
  k_prefix<<<1, NBIN, 0, stream>>>(hist, binb, cursor, counters);
  k_scatter<<<nbS, 1024, 0, stream>>>(src, dst, ne, shift, cursor, sorted);
  k_c1<<<NBIN, 256, 0, stream>>>(sorted, binb, hist, xw, dinv, y, n, shift);
  k_c2<<<NBIN, 256, 0, stream>>>(sorted, binb, hist, y, xw, dinv, batch, gcn_b,
                                 topk_w, s_raw, smax_e, n, shift);
  k_ex<<<nbN, 256, 0, stream>>>(s_raw, batch, smax_e, ex, sumex, n);
  k_compact_n<<<nbN, 256, 0, stream>>>(ex, sumex, batch, x, kmap, kbatch, hk, tx0,
                                       degfc, counters, n, kcap);
  k_compact_e<<<NBIN, 256, 0, stream>>>(sorted, binb, hist, kmap, eks, ekd, degfc,
                                        counters, n, shift, ecap);

  k_edge_agg<1><<<64, 256, 0, stream>>>(eks, ekd, degfc, hk, tx0, counters, ecap);
  k_mm<2><<<128, GW, 0, stream>>>(hk, tx0, c0w0, c0w1, c0b,
                                  bng + 0 * GW, bnb + 0 * GW, bnm + 0 * GW, bnv + 0 * GW,
                                  0 * GW, kbatch, counters, kcap, hA, gmax_e, tx);
  k_edge_agg<7><<<64, 256, 0, stream>>>(eks, ekd, degfc, hA, tx, counters, ecap);
  k_mm<GW><<<128, GW, 0, stream>>>(hA, tx, c1w0, c1w1, c1b,
                                   bng + 1 * GW, bnb + 1 * GW, bnm + 1 * GW, bnv + 1 * GW,
                                   1 * GW, kbatch, counters, kcap, hB, gmax_e, tx);
  k_edge_agg<7><<<64, 256, 0, stream>>>(eks, ekd, degfc, hB, tx, counters, ecap);
  k_mm<GW><<<128, GW, 0, stream>>>(hB, tx, c2w0, c2w1, c2b,
                                   bng + 2 * GW, bnb + 2 * GW, bnm + 2 * GW, bnv + 2 * GW,
                                   2 * GW, kbatch, counters, kcap, hA, gmax_e, nullptr);

  k_final<<<NG, 64, 0, stream>>>(gmax_e, l0w, l0b, l1w, l1b, lfw, lfb, out);
}

// Round 5
// 102.051 us; speedup vs baseline: 1.6539x; 1.2235x over previous
//
#include <hip/hip_runtime.h>
#include <math.h>

#define NG 16
#define GW 128
#define NEGV -1.0e9f
#define EPSBN 1e-5f
#define MIN_SCORE 0.1f
#define TOLK 1e-7f
#define NBIN 1024
#define NPBMAX 256
#define EPT 16           // edges per thread in scatter
#define KCAP 256         // global kept-node cap (math bound: <=16*9 + tie slack)
#define ECAP 2048        // surviving-edge cap
#define ROWCAP 16        // per-graph LDS fast-path row cap
#define LECAP 256        // per-graph LDS fast-path edge cap

// ---------- helpers ----------
__device__ __forceinline__ unsigned encf(float f) {
  unsigned u = __float_as_uint(f);
  return (u & 0x80000000u) ? ~u : (u | 0x80000000u);
}
__device__ __forceinline__ float decf(unsigned u) {
  unsigned b = (u & 0x80000000u) ? (u & 0x7fffffffu) : ~u;
  return __uint_as_float(b);
}
__device__ __forceinline__ float eluf(float v) { return v > 0.0f ? v : expm1f(v); }

// ---------- kernels ----------
__global__ void k_zero(int* __restrict__ bincnt, int* __restrict__ counters,
                       unsigned* __restrict__ smax_e, float* __restrict__ sumex) {
  int t = threadIdx.x;
  for (int i = t; i < NBIN; i += blockDim.x) bincnt[i] = 0;
  if (t < NG) { smax_e[t] = encf(-INFINITY); sumex[t] = 0.0f; }
  if (t == 0) { counters[0] = 0; counters[1] = 0; }
}

// direct bucketed scatter (per-bin capacity regions) + xw init
__global__ __launch_bounds__(1024) void k_scatter(
    const int* __restrict__ src, const int* __restrict__ dst, int ne, int shift,
    int cap, int* __restrict__ bincnt, unsigned* __restrict__ sorted,
    const float* __restrict__ x, const float* __restrict__ gcn_w,
    float* __restrict__ xw, int n) {
  __shared__ int lh[NBIN];
  __shared__ int gb[NBIN];
  int t = threadIdx.x;
  long gid = (long)blockIdx.x * 1024 + t;
  long gs = (long)gridDim.x * 1024;
  float w0 = gcn_w[0], w1 = gcn_w[1];
  for (long i = gid; i < n; i += gs) xw[i] = x[2 * i] * w0 + x[2 * i + 1] * w1;
  for (int b = t; b < NBIN; b += 1024) lh[b] = 0;
  __syncthreads();
  long ebase = (long)blockIdx.x * (1024 * EPT);
  int rank[EPT], dv[EPT];
  #pragma unroll
  for (int k = 0; k < EPT; ++k) {
    long e = ebase + (long)k * 1024 + t;
    rank[k] = 0; dv[k] = 0;
    if (e < ne) { dv[k] = dst[e]; rank[k] = atomicAdd(&lh[dv[k] >> shift], 1); }
  }
  __syncthreads();
  for (int b = t; b < NBIN; b += 1024)
    gb[b] = lh[b] ? atomicAdd(&bincnt[b], lh[b]) : 0;
  __syncthreads();
  #pragma unroll
  for (int k = 0; k < EPT; ++k) {
    long e = ebase + (long)k * 1024 + t;
    if (e < ne) {
      int d = dv[k], bin = d >> shift;
      int pos = gb[bin] + rank[k];
      if (pos < cap)
        sorted[(size_t)bin * cap + pos] =
            ((unsigned)(d & ((1 << shift) - 1)) << 24) | (unsigned)src[e];
    }
  }
}

// per-bucket: deg count (LDS) -> dinv + y = xw*dinv
__global__ void k_c1(const unsigned* __restrict__ sorted, const int* __restrict__ bincnt,
                     int cap, const float* __restrict__ xw, float* __restrict__ dinv,
                     float* __restrict__ y, int n, int shift) {
  __shared__ int ldeg[NPBMAX];
  int b = blockIdx.x;
  int off = b << shift;
  if (off >= n) return;
  int npb = 1 << shift;
  int t = threadIdx.x;
  for (int j = t; j < npb; j += blockDim.x) ldeg[j] = 0;
  __syncthreads();
  size_t s0 = (size_t)b * cap;
  int cnt = bincnt[b]; if (cnt > cap) cnt = cap;
  for (int i = t; i < cnt; i += blockDim.x)
    atomicAdd(&ldeg[sorted[s0 + i] >> 24], 1);
  __syncthreads();
  for (int j = t; j < npb; j += blockDim.x) {
    int g = off + j;
    if (g < n) {
      float dv = rsqrtf((float)(ldeg[j] + 1));   // +1 self loop
      dinv[g] = dv;
      y[g] = xw[g] * dv;
    }
  }
}

// per-bucket: agg -> s_raw; per-graph max AND unnormalized sum(exp(s))
__global__ void k_c2(const unsigned* __restrict__ sorted, const int* __restrict__ bincnt,
                     int cap, const float* __restrict__ y, const float* __restrict__ xw,
                     const float* __restrict__ dinv, const int* __restrict__ batch,
                     const float* __restrict__ gcn_b, const float* __restrict__ topk_w,
                     float* __restrict__ s_raw, unsigned* __restrict__ smax_e,
                     float* __restrict__ sumex, int n, int shift) {
  __shared__ float lt[NPBMAX];
  __shared__ unsigned ls[NG];
  __shared__ float lsum[NG];
  int b = blockIdx.x;
  int off = b << shift;
  if (off >= n) return;
  int npb = 1 << shift;
  int t = threadIdx.x;
  for (int j = t; j < npb; j += blockDim.x) lt[j] = 0.0f;
  if (t < NG) { ls[t] = encf(-INFINITY); lsum[t] = 0.0f; }
  __syncthreads();
  size_t s0 = (size_t)b * cap;
  int cnt = bincnt[b]; if (cnt > cap) cnt = cap;
  for (int i = t; i < cnt; i += blockDim.x) {
    unsigned p = sorted[s0 + i];
    atomicAdd(&lt[p >> 24], y[p & 0xFFFFFFu]);
  }
  __syncthreads();
  float gb_ = gcn_b[0], tw = topk_w[0];
  for (int j = t; j < npb; j += blockDim.x) {
    int g = off + j;
    if (g < n) {
      float dv = dinv[g];
      float attn = dv * lt[j] + xw[g] * dv * dv + gb_;
      float s = attn * tw;
      s_raw[g] = s;
      int bb = batch[g];
      atomicMax(&ls[bb], encf(s));
      atomicAdd(&lsum[bb], expf(s));
    }
  }
  __syncthreads();
  if (t < NG) {
    if (ls[t] != encf(-INFINITY)) atomicMax(&smax_e[t], ls[t]);
    if (lsum[t] != 0.0f) atomicAdd(&sumex[t], lsum[t]);
  }
}

__global__ void k_compact_n(const float* __restrict__ s_raw, const float* __restrict__ sumex,
                            const unsigned* __restrict__ smax_e,
                            const int* __restrict__ batch, const float* __restrict__ x,
                            int* __restrict__ kmap, int* __restrict__ kbatch,
                            float* __restrict__ hk, float* __restrict__ degfc,
                            int* __restrict__ counters, int n) {
  int i = blockIdx.x * blockDim.x + threadIdx.x;
  if (i >= n) return;
  if (i < KCAP) degfc[i] = 0.0f;                  // idempotent pre-zero for compact_e
  int b = batch[i];
  float se = sumex[b];
  float score = expf(s_raw[i]) / se;
  float ms = expf(decf(smax_e[b])) / se;          // == max over nodes of score (monotone fp)
  float thr = fminf(ms - TOLK, MIN_SCORE);
  int m = -1;
  if (score > thr) {
    int idx = atomicAdd(&counters[0], 1);
    if (idx < KCAP) {
      m = idx;
      kbatch[idx] = b;
      hk[2 * idx]     = x[2 * i] * score;
      hk[2 * idx + 1] = x[2 * i + 1] * score;
    }
  }
  kmap[i] = m;
}

// per-bucket surviving-edge compaction
__global__ void k_compact_e(const unsigned* __restrict__ sorted, const int* __restrict__ bincnt,
                            int cap, const int* __restrict__ kmap,
                            int* __restrict__ eks, int* __restrict__ ekd,
                            float* __restrict__ degfc, int* __restrict__ counters,
                            int n, int shift) {
  int b = blockIdx.x;
  int off = b << shift;
  if (off >= n) return;
  size_t s0 = (size_t)b * cap;
  int cnt = bincnt[b]; if (cnt > cap) cnt = cap;
  for (int i = threadIdx.x; i < cnt; i += blockDim.x) {
    unsigned p = sorted[s0 + i];
    int ks = kmap[p & 0xFFFFFFu];
    if (ks < 0) continue;
    int kd = kmap[off + (int)(p >> 24)];
    if (kd < 0) continue;
    int j = atomicAdd(&counters[1], 1);
    if (j < ECAP) {
      eks[j] = ks;
      ekd[j] = kd;
      atomicAdd(&degfc[kd], 1.0f);
    }
  }
}

// one cheb layer (L=1 or 2) inside the per-graph tail block
__device__ void tail_layer(const float* hin, float* tx, float* hout,
                           const float* __restrict__ w0, const float* __restrict__ w1,
                           const float* __restrict__ cb,
                           const float* __restrict__ bng, const float* __restrict__ bnb,
                           const float* __restrict__ bnm, const float* __restrict__ bnv,
                           int L, int R, int LE, int S, bool fast,
                           const int* les, const int* led, const float* lenf,
                           const int* kl, const int* rows_g,
                           const int* __restrict__ kbatch,
                           const int* __restrict__ eks, const int* __restrict__ ekd,
                           const float* __restrict__ degfc,
                           unsigned* lgm, int g, int t) {
  for (int i = t; i < R * GW; i += 256) tx[i] = 0.0f;
  __syncthreads();
  if (fast) {
    for (int idx = t; idx < LE * GW; idx += 256) {
      int e = idx >> 7, c = idx & 127;
      int sr = kl[les[e]];
      if (sr >= 0) atomicAdd(&tx[led[e] * GW + c], -hin[sr * GW + c] * lenf[e]);
    }
  } else {
    for (int e = t; e < S; e += 256) {
      int kd = ekd[e];
      int dr = kl[kd];
      if (dr < 0) continue;
      int sr = kl[eks[e]];
      if (sr < 0) continue;
      float dfs = degfc[eks[e]], dfd = degfc[kd];
      float nf = (dfs > 0.f ? rsqrtf(dfs) : 0.f) * (dfd > 0.f ? rsqrtf(dfd) : 0.f);
      for (int c = 0; c < GW; ++c)
        atomicAdd(&tx[dr * GW + c], -hin[sr * GW + c] * nf);
    }
  }
  __syncthreads();
  int j = t & 127, ih = t >> 7;
  float sc = bng[L * GW + j] * rsqrtf(bnv[L * GW + j] + EPSBN);
  float mn = bnm[L * GW + j], bt = bnb[L * GW + j], bj = cb[j];
  for (int i = ih; i < R; i += 2) {
    float acc = bj;
    for (int k = 0; k < GW; ++k)
      acc += hin[i * GW + k] * w0[k * GW + j] + tx[i * GW + k] * w1[k * GW + j];
    float v = eluf(acc);
    v = (v - mn) * sc + bt;
    if (hout) hout[i * GW + j] = v;
    if (kbatch[rows_g[i]] == g) atomicMax(&lgm[L * GW + j], encf(v));
  }
  __syncthreads();
}

// 16 blocks, one per graph: 2-hop-halo rows, 3x(agg+cheb+bn), gmax in LDS, MLP, out
__global__ __launch_bounds__(256) void k_tail(
    const float* __restrict__ hk, const int* __restrict__ kbatch,
    const int* __restrict__ counters,
    const int* __restrict__ eks, const int* __restrict__ ekd,
    const float* __restrict__ degfc,
    const float* __restrict__ c0w0, const float* __restrict__ c0w1, const float* __restrict__ c0b,
    const float* __restrict__ c1w0, const float* __restrict__ c1w1, const float* __restrict__ c1b,
    const float* __restrict__ c2w0, const float* __restrict__ c2w1, const float* __restrict__ c2b,
    const float* __restrict__ bng, const float* __restrict__ bnb,
    const float* __restrict__ bnm, const float* __restrict__ bnv,
    const float* __restrict__ l0w, const float* __restrict__ l0b,
    const float* __restrict__ l1w, const float* __restrict__ l1b,
    const float* __restrict__ lfw, const float* __restrict__ lfb,
    float* __restrict__ g_hA, float* __restrict__ g_hB, float* __restrict__ g_tx,
    float* __restrict__ g_t0, float* __restrict__ out) {
  __shared__ float sA[ROWCAP * GW], sB[ROWCAP * GW], sT[ROWCAP * GW];
  __shared__ float t0v[ROWCAP * 2];
  __shared__ int kl[KCAP];
  __shared__ int rows_g[KCAP];
  __shared__ int les[LECAP], led[LECAP];
  __shared__ float lenf[LECAP];
  __shared__ unsigned lgm[3 * GW];
  __shared__ int cnts[2];
  __shared__ float mlp0[32], mlp1[8], lg3[3];

  int g = blockIdx.x, t = threadIdx.x;
  int K = counters[0]; if (K > KCAP) K = KCAP;
  int S = counters[1]; if (S > ECAP) S = ECAP;
  if (t == 0) { cnts[0] = 0; cnts[1] = 0; }
  for (int i = t; i < KCAP; i += 256) kl[i] = -1;
  for (int i = t; i < 3 * GW; i += 256) lgm[i] = encf(NEGV);
  __syncthreads();
  // own rows
  for (int i = t; i < K; i += 256)
    if (kbatch[i] == g) { int r = atomicAdd(&cnts[0], 1); rows_g[r] = i; }
  __syncthreads();
  int R0 = cnts[0];
  for (int r = t; r < R0; r += 256) kl[rows_g[r]] = r;
  __syncthreads();
  // 2-hop halo expansion (serial, S is tiny)
  if (t == 0) {
    for (int pass = 0; pass < 2; ++pass) {
      int Rcur = cnts[0];
      for (int e = 0; e < S; ++e) {
        int kd = ekd[e];
        if (kl[kd] >= 0 && kl[kd] < Rcur) {
          int ks = eks[e];
          if (kl[ks] < 0) { int r = cnts[0]++; rows_g[r] = ks; kl[ks] = r; }
        }
      }
    }
  }
  __syncthreads();
  int R = cnts[0];                      // R <= K <= KCAP always
  // local edge list (edges into any local row)
  for (int e = t; e < S; e += 256) {
    int kd = ekd[e];
    if (kl[kd] >= 0) {
      int j = atomicAdd(&cnts[1], 1);
      if (j < LECAP) {
        les[j] = eks[e];
        led[j] = kl[kd];
        float dfs = degfc[eks[e]], dfd = degfc[kd];
        lenf[j] = (dfs > 0.f ? rsqrtf(dfs) : 0.f) * (dfd > 0.f ? rsqrtf(dfd) : 0.f);
      }
    }
  }
  __syncthreads();
  int LE = cnts[1]; if (LE > LECAP) LE = LECAP;
  bool fast = (R <= ROWCAP) && (cnts[1] <= LECAP);
  float* hA  = fast ? sA  : g_hA + (size_t)g * KCAP * GW;
  float* hB  = fast ? sB  : g_hB + (size_t)g * KCAP * GW;
  float* tx  = fast ? sT  : g_tx + (size_t)g * KCAP * GW;
  float* t0p = fast ? t0v : g_t0 + (size_t)g * KCAP * 2;

  // --- layer 0 (D=2) ---
  for (int i = t; i < R * 2; i += 256) t0p[i] = 0.0f;
  __syncthreads();
  if (fast) {
    for (int idx = t; idx < LE * 2; idx += 256) {
      int e = idx >> 1, c = idx & 1;
      atomicAdd(&t0p[led[e] * 2 + c], -hk[les[e] * 2 + c] * lenf[e]);
    }
  } else {
    for (int e = t; e < S; e += 256) {
      int kd = ekd[e];
      int dr = kl[kd];
      if (dr < 0) continue;
      int ks = eks[e];
      float dfs = degfc[ks], dfd = degfc[kd];
      float nf = (dfs > 0.f ? rsqrtf(dfs) : 0.f) * (dfd > 0.f ? rsqrtf(dfd) : 0.f);
      atomicAdd(&t0p[dr * 2],     -hk[ks * 2] * nf);
      atomicAdd(&t0p[dr * 2 + 1], -hk[ks * 2 + 1] * nf);
    }
  }
  __syncthreads();
  {
    int j = t & 127, ih = t >> 7;
    float sc = bng[j] * rsqrtf(bnv[j] + EPSBN);
    float mn = bnm[j], bt = bnb[j];
    for (int i = ih; i < R; i += 2) {
      int gi = rows_g[i];
      float acc = c0b[j] + hk[gi * 2] * c0w0[j] + hk[gi * 2 + 1] * c0w0[GW + j]
                + t0p[i * 2] * c0w1[j] + t0p[i * 2 + 1] * c0w1[GW + j];
      float v = eluf(acc);
      v = (v - mn) * sc + bt;
      hA[i * GW + j] = v;
      if (kbatch[gi] == g) atomicMax(&lgm[j], encf(v));
    }
  }
  __syncthreads();
  // --- layers 1,2 ---
  tail_layer(hA, tx, hB, c1w0, c1w1, c1b, bng, bnb, bnm, bnv, 1, R, LE, S, fast,
             les, led, lenf, kl, rows_g, kbatch, eks, ekd, degfc, lgm, g, t);
  tail_layer(hB, tx, nullptr, c2w0, c2w1, c2b, bng, bnb, bnm, bnv, 2, R, LE, S, fast,
             les, led, lenf, kl, rows_g, kbatch, eks, ekd, degfc, lgm, g, t);
  // --- MLP + log_softmax ---
  if (t < 32) {
    float acc = l0b[t];
    for (int k = 0; k < 3 * GW; ++k) acc += decf(lgm[k]) * l0w[k * 32 + t];
    mlp0[t] = eluf(acc);
  }
  __syncthreads();
  if (t < 8) {
    float acc = l1b[t];
    for (int k = 0; k < 32; ++k) acc += mlp0[k] * l1w[k * 8 + t];
    mlp1[t] = eluf(acc);
  }
  __syncthreads();
  if (t < 3) {
    float acc = lfb[t];
    for (int k = 0; k < 8; ++k) acc += mlp1[k] * lfw[k * 3 + t];
    lg3[t] = acc;
  }
  __syncthreads();
  if (t == 0) {
    float a = lg3[0], b = lg3[1], c = lg3[2];
    float m = fmaxf(a, fmaxf(b, c));
    float ls = m + logf(expf(a - m) + expf(b - m) + expf(c - m));
    out[g * 3 + 0] = a - ls;
    out[g * 3 + 1] = b - ls;
    out[g * 3 + 2] = c - ls;
  }
}

// ---------- launcher ----------
extern "C" void kernel_launch(void* const* d_in, const int* in_sizes, int n_in,
                              void* d_out, int out_size, void* d_ws, size_t ws_size,
                              hipStream_t stream) {
  const float* x      = (const float*)d_in[0];
  const int*   ei     = (const int*)d_in[1];
  const int*   batch  = (const int*)d_in[2];
  const float* gcn_w  = (const float*)d_in[3];
  const float* gcn_b  = (const float*)d_in[4];
  const float* topk_w = (const float*)d_in[5];
  const float* c0w0 = (const float*)d_in[6],  *c0w1 = (const float*)d_in[7],  *c0b = (const float*)d_in[8];
  const float* c1w0 = (const float*)d_in[9],  *c1w1 = (const float*)d_in[10], *c1b = (const float*)d_in[11];
  const float* c2w0 = (const float*)d_in[12], *c2w1 = (const float*)d_in[13], *c2b = (const float*)d_in[14];
  const float* bng = (const float*)d_in[15], *bnb = (const float*)d_in[16];
  const float* bnm = (const float*)d_in[17], *bnv = (const float*)d_in[18];
  const float* l0w = (const float*)d_in[19], *l0b = (const float*)d_in[20];
  const float* l1w = (const float*)d_in[21], *l1b = (const float*)d_in[22];
  const float* lfw = (const float*)d_in[23], *lfb = (const float*)d_in[24];
  float* out = (float*)d_out;

  const int n  = in_sizes[2];       // N nodes
  const int ne = in_sizes[1] / 2;   // E edges
  const int* src = ei;
  const int* dst = ei + ne;

  int shift = 0;
  while (((n - 1) >> shift) >= NBIN) shift++;
  if (shift > 8) shift = 8;  // supports n <= 262144 (payload dl fits 8 bits)
  const int nbins = ((n - 1) >> shift) + 1;
  int avg = (ne + nbins - 1) / nbins;
  int cap = avg + (int)(8.0 * sqrt((double)avg)) + 64;
  cap = (cap + 15) & ~15;

  char* bp = (char*)d_ws;
  size_t off = 0;
  auto A = [&](size_t bytes) -> void* {
    void* r = (void*)(bp + off);
    off += (bytes + 255) & ~(size_t)255;
    return r;
  };
  float*    xw     = (float*)A((size_t)n * 4);
  float*    dinv   = (float*)A((size_t)n * 4);
  float*    y      = (float*)A((size_t)n * 4);
  float*    s_raw  = (float*)A((size_t)n * 4);
  int*      kmap   = (int*)A((size_t)n * 4);
  unsigned* sorted = (unsigned*)A((size_t)NBIN * cap * 4);
  int*      bincnt = (int*)A(NBIN * 4);
  unsigned* smax_e = (unsigned*)A(NG * 4);
  float*    sumex  = (float*)A(NG * 4);
  int*      counters = (int*)A(8);
  int*      kbatch = (int*)A((size_t)KCAP * 4);
  float*    degfc  = (float*)A((size_t)KCAP * 4);
  float*    hk     = (float*)A((size_t)KCAP * 8);
  int*      eks    = (int*)A((size_t)ECAP * 4);
  int*      ekd    = (int*)A((size_t)ECAP * 4);
  float*    g_hA   = (float*)A((size_t)NG * KCAP * GW * 4);
  float*    g_hB   = (float*)A((size_t)NG * KCAP * GW * 4);
  float*    g_tx   = (float*)A((size_t)NG * KCAP * GW * 4);
  float*    g_t0   = (float*)A((size_t)NG * KCAP * 8);

  const int nbN = (n + 255) / 256;
  const int nbS = (ne + 1024 * EPT - 1) / (1024 * EPT);

  k_zero<<<1, 1024, 0, stream>>>(bincnt, counters, smax_e, sumex);
  k_scatter<<<nbS, 1024, 0, stream>>>(src, dst, ne, shift, cap, bincnt, sorted,
                                      x, gcn_w, xw, n);
  k_c1<<<NBIN, 256, 0, stream>>>(sorted, bincnt, cap, xw, dinv, y, n, shift);
  k_c2<<<NBIN, 256, 0, stream>>>(sorted, bincnt, cap, y, xw, dinv, batch, gcn_b,
                                 topk_w, s_raw, smax_e, sumex, n, shift);
  k_compact_n<<<nbN, 256, 0, stream>>>(s_raw, sumex, smax_e, batch, x, kmap,
                                       kbatch, hk, degfc, counters, n);
  k_compact_e<<<NBIN, 256, 0, stream>>>(sorted, bincnt, cap, kmap, eks, ekd,
                                        degfc, counters, n, shift);
  k_tail<<<NG, 256, 0, stream>>>(hk, kbatch, counters, eks, ekd, degfc,
                                 c0w0, c0w1, c0b, c1w0, c1w1, c1b, c2w0, c2w1, c2b,
                                 bng, bnb, bnm, bnv, l0w, l0b, l1w, l1b, lfw, lfb,
                                 g_hA, g_hB, g_tx, g_t0, out);
}